// Round 4
// baseline (406.795 us; speedup 1.0000x reference)
//
#include <hip/hip_runtime.h>
#include <stdint.h>

typedef _Float16 f16;
typedef _Float16 f16x8 __attribute__((ext_vector_type(8)));
typedef _Float16 f16x4 __attribute__((ext_vector_type(4)));
typedef _Float16 f16x2 __attribute__((ext_vector_type(2)));
typedef float f32x4 __attribute__((ext_vector_type(4)));

__device__ __forceinline__ f32x4 mfma16(f16x8 a, f16x8 b, f32x4 c) {
    return __builtin_amdgcn_mfma_f32_16x16x32_f16(a, b, c, 0, 0, 0);
}

// Async global->LDS, 16B per lane. LDS dest = wave-uniform base + lane*16.
__device__ __forceinline__ void gload16(const f16* g, f16* l) {
    __builtin_amdgcn_global_load_lds(
        (const __attribute__((address_space(1))) uint32_t*)g,
        (__attribute__((address_space(3))) uint32_t*)l, 16, 0, 0);
}

// ---------------------------------------------------------------------------
// Shared GEMM body: C[m][n] = (sum_k A[m*1024+k]*B[n*1024+k] + bias) * scale.
// K=1024. 128x128 tile, 4 waves 2x2, 16x16x32 f16 MFMA, global_load_lds
// staging with XOR chunk swizzle folded into per-lane source addresses.
// ---------------------------------------------------------------------------
template <bool OUT16>
__device__ __forceinline__ void gemm_body(const f16* __restrict__ A,
                                          const f16* __restrict__ B,
                                          const float* __restrict__ bias,
                                          void* __restrict__ Cout, long ldo,
                                          int biasrow, float scale,
                                          long m0, long n0, f16* As, f16* Bs) {
    int tid = threadIdx.x;
    int lane = tid & 63, w = tid >> 6;
    int wm = w & 1, wn = w >> 1;
    int l15 = lane & 15, quad = lane >> 4;

    int rg = lane >> 3;        // row within 8-row staging group
    int cg = (lane & 7) ^ rg;  // global chunk index (swizzled)
    const f16* ag[4];
    const f16* bg[4];
    f16* al[4];
    f16* bl[4];
#pragma unroll
    for (int t = 0; t < 4; ++t) {
        int rb = (w * 4 + t) * 8;
        ag[t] = A + (m0 + rb + rg) * 1024 + cg * 8;
        bg[t] = B + (n0 + rb + rg) * 1024 + cg * 8;
        al[t] = &As[rb * 64];
        bl[t] = &Bs[rb * 64];
    }

    f32x4 acc[4][4] = {};

    for (int k0 = 0; k0 < 1024; k0 += 64) {
        __syncthreads();
#pragma unroll
        for (int t = 0; t < 4; ++t) {
            gload16(ag[t] + k0, al[t]);
            gload16(bg[t] + k0, bl[t]);
        }
        __syncthreads();
#pragma unroll
        for (int ks = 0; ks < 2; ++ks) {
            int cc = (ks * 4 + quad) ^ (l15 & 7);
            f16x8 af[4], bf[4];
#pragma unroll
            for (int t = 0; t < 4; ++t) {
                af[t] = *(const f16x8*)&As[(wm * 64 + t * 16 + l15) * 64 + cc * 8];
                bf[t] = *(const f16x8*)&Bs[(wn * 64 + t * 16 + l15) * 64 + cc * 8];
            }
#pragma unroll
            for (int i = 0; i < 4; ++i)
#pragma unroll
                for (int j = 0; j < 4; ++j)
                    acc[i][j] = mfma16(af[i], bf[j], acc[i][j]);
        }
    }

    // C/D layout: col = lane&15, row = quad*4 + reg
#pragma unroll
    for (int i = 0; i < 4; ++i) {
        int mrow = wm * 64 + i * 16 + quad * 4;
#pragma unroll
        for (int j = 0; j < 4; ++j) {
            int ncol = wn * 64 + j * 16 + l15;
            long gn = n0 + ncol;
#pragma unroll
            for (int r = 0; r < 4; ++r) {
                long gm = m0 + mrow + r;
                float v = (acc[i][j][r] + (biasrow ? bias[gm] : bias[gn])) * scale;
                if constexpr (OUT16)
                    ((f16*)Cout)[gm * ldo + gn] = (f16)v;
                else
                    ((float*)Cout)[gm * ldo + gn] = v;
            }
        }
    }
}

// Merged Q/K/V projection: grid (64, 8, 3); z selects operand set.
// z=0: Qp = (q@Wq^T+bq)*log2e/32  (softmax scale folded -> attn uses exp2)
// z=1: Kp = k@Wk^T+bk
// z=2: Vt = (v@Wv^T+bv)^T  computed as Wv x v^T -> [e][tok], bias per row
__global__ __launch_bounds__(256, 4) void qkv_proj(
    const f16* __restrict__ qh, const f16* __restrict__ kh,
    const f16* __restrict__ vh, const f16* __restrict__ Wh,
    const float* __restrict__ bq, const float* __restrict__ bk,
    const float* __restrict__ bv, f16* __restrict__ Qp, f16* __restrict__ Kp,
    f16* __restrict__ Vt) {
    __shared__ __align__(16) f16 As[128 * 64];
    __shared__ __align__(16) f16 Bs[128 * 64];
    int z = blockIdx.z;
    const f16* A;
    const f16* B;
    const float* bias;
    f16* C;
    long ldo;
    int biasrow;
    float scale;
    if (z == 0) {
        A = qh; B = Wh; bias = bq; C = Qp; ldo = 1024; biasrow = 0;
        scale = 0.0450842200277786f;  // log2(e)/32
    } else if (z == 1) {
        A = kh; B = Wh + 1048576; bias = bk; C = Kp; ldo = 1024; biasrow = 0;
        scale = 1.0f;
    } else {
        A = Wh + 2097152; B = vh; bias = bv; C = Vt; ldo = 8192; biasrow = 1;
        scale = 1.0f;
    }
    long m0 = (long)(z == 2 ? blockIdx.y : blockIdx.x) * 128;
    long n0 = (long)(z == 2 ? blockIdx.x : blockIdx.y) * 128;
    gemm_body<true>(A, B, bias, C, ldo, biasrow, scale, m0, n0, As, Bs);
}

// Output projection: out = Op@Wo^T + bo (fp32 out)
__global__ __launch_bounds__(256, 4) void o_proj(const f16* __restrict__ Op,
                                                 const f16* __restrict__ Wo,
                                                 const float* __restrict__ bo,
                                                 float* __restrict__ out) {
    __shared__ __align__(16) f16 As[128 * 64];
    __shared__ __align__(16) f16 Bs[128 * 64];
    gemm_body<false>(Op, Wo, bo, out, 1024, 0, 1.0f, (long)blockIdx.x * 128,
                     (long)blockIdx.y * 128, As, Bs);
}

// ---------------------------------------------------------------------------
// Attention: one block per (n, h, 128-q-tile); 32 k-tiles of 64. Unnormalized
// accumulation (logits bounded), divide by rowsum at end. Qp pre-scaled by
// log2e/32 -> P = exp2(S), no per-element multiply. K/V double-buffered via
// global_load_lds prefetch. QPs holds Q then is reused for P (rows are
// wave-private -> no barrier between pack and PV; ONE barrier per k-tile).
// XCD-swizzled grid: all 16 q-tiles of one (n,h) on one XCD.
// ---------------------------------------------------------------------------
__global__ __launch_bounds__(256, 3) void attn128(const f16* __restrict__ Qp,
                                                  const f16* __restrict__ Kp,
                                                  const f16* __restrict__ Vt,
                                                  f16* __restrict__ Op) {
    __shared__ __align__(16) f16 QPs[128 * 64];
    __shared__ __align__(16) f16 Ks[2][64 * 64];
    __shared__ __align__(16) f16 Vs[2][64 * 64];
    __shared__ float lsi[128];

    int tid = threadIdx.x;
    int lane = tid & 63, w = tid >> 6;
    int l15 = lane & 15, quad = lane >> 4;
    int b = blockIdx.x;
    int xcd = b & 7, slot = b >> 3;
    int nh = xcd * 8 + (slot >> 4);  // blocks of one (n,h) share an XCD
    int qt = slot & 15;
    int nb = nh >> 4, h = nh & 15;
    long tok0 = (long)nb * 2048;

    int rg = lane >> 3, cg = (lane & 7) ^ rg;

    // stage Q tile (wave-private rows)
    const f16* qsrc = Qp + (tok0 + qt * 128) * 1024 + h * 64;
#pragma unroll
    for (int t = 0; t < 4; ++t) {
        int rb = w * 32 + t * 8;
        gload16(qsrc + (rb + rg) * 1024 + cg * 8, &QPs[rb * 64]);
    }
    // per-lane K/V source pointers (kt = 0) and running prefetch pointers
    const f16* kptr = Kp + (tok0 + w * 16 + rg) * 1024 + h * 64 + cg * 8;
    const f16* vptr = Vt + ((long)h * 64 + w * 16 + rg) * 8192 + tok0 + cg * 8;
    gload16(kptr, &Ks[0][(w * 16) * 64]);
    gload16(kptr + 8 * 1024, &Ks[0][(w * 16 + 8) * 64]);
    gload16(vptr, &Vs[0][(w * 16) * 64]);
    gload16(vptr + (long)8 * 8192, &Vs[0][(w * 16 + 8) * 64]);
    const f16* kn = kptr + 65536;  // +64 rows * 1024
    const f16* vn = vptr + 64;     // +64 tokens
    __syncthreads();

    // Q fragments are loop-invariant: hoist (QPs becomes P storage after this)
    f16x8 qf[2][2];
#pragma unroll
    for (int ks = 0; ks < 2; ++ks) {
        int cc = (ks * 4 + quad) ^ (l15 & 7);
#pragma unroll
        for (int j = 0; j < 2; ++j)
            qf[ks][j] = *(const f16x8*)&QPs[(w * 32 + j * 16 + l15) * 64 + cc * 8];
    }

    f32x4 oacc[2][4] = {};
    float rsum[2] = {0.f, 0.f};
    const f32x4 z4 = {0.f, 0.f, 0.f, 0.f};

    for (int kt = 0; kt < 32; ++kt) {
        int cur = kt & 1;
        // S^T = K(64 rows) x Q^T; D[k][q], wave w owns q in [w*32, w*32+32)
        f32x4 sacc[4][2];
        {
            int cc0 = quad ^ (l15 & 7);
            int cc1 = (4 + quad) ^ (l15 & 7);
            f16x8 a0[4], a1[4];
#pragma unroll
            for (int t = 0; t < 4; ++t) {
                a0[t] = *(const f16x8*)&Ks[cur][(t * 16 + l15) * 64 + cc0 * 8];
                a1[t] = *(const f16x8*)&Ks[cur][(t * 16 + l15) * 64 + cc1 * 8];
            }
#pragma unroll
            for (int i = 0; i < 4; ++i)
#pragma unroll
                for (int j = 0; j < 2; ++j) {
                    sacc[i][j] = mfma16(a0[i], qf[0][j], z4);
                    sacc[i][j] = mfma16(a1[i], qf[1][j], sacc[i][j]);
                }
        }
        // async prefetch of next K/V tile (overlaps exp/pack below)
        if (kt < 31) {
            int nxt = cur ^ 1;
            f16* kd = &Ks[nxt][(w * 16) * 64];
            f16* vd = &Vs[nxt][(w * 16) * 64];
            gload16(kn, kd);
            gload16(kn + 8 * 1024, kd + 8 * 64);
            gload16(vn, vd);
            gload16(vn + (long)8 * 8192, vd + 8 * 64);
            kn += 65536;
            vn += 64;
        }
        // P = exp2(S); rowsum; pack into QPs (wave-private rows)
#pragma unroll
        for (int i = 0; i < 4; ++i) {
#pragma unroll
            for (int j = 0; j < 2; ++j) {
                float p0 = __builtin_exp2f(sacc[i][j][0]);
                float p1 = __builtin_exp2f(sacc[i][j][1]);
                float p2 = __builtin_exp2f(sacc[i][j][2]);
                float p3 = __builtin_exp2f(sacc[i][j][3]);
                rsum[j] += (p0 + p1) + (p2 + p3);
                f16x2 lo = __builtin_bit_cast(f16x2, __builtin_amdgcn_cvt_pkrtz(p0, p1));
                f16x2 hi = __builtin_bit_cast(f16x2, __builtin_amdgcn_cvt_pkrtz(p2, p3));
                f16x4 ph;
                ph[0] = lo[0]; ph[1] = lo[1]; ph[2] = hi[0]; ph[3] = hi[1];
                int qrow = w * 32 + j * 16 + l15;
                int kl = i * 16 + quad * 4;
                int c = kl >> 3;
                *(f16x4*)&QPs[qrow * 64 + ((c ^ (qrow & 7)) << 3) + (kl & 7)] = ph;
            }
        }
        // O += P(q,k) x V(d,k)^T  (same-wave LDS ordering: no barrier needed)
#pragma unroll
        for (int ks = 0; ks < 2; ++ks) {
            int cc = (ks * 4 + quad) ^ (l15 & 7);
            f16x8 af[2], bf[4];
#pragma unroll
            for (int i = 0; i < 2; ++i)
                af[i] = *(const f16x8*)&QPs[(w * 32 + i * 16 + l15) * 64 + cc * 8];
#pragma unroll
            for (int j = 0; j < 4; ++j)
                bf[j] = *(const f16x8*)&Vs[cur][(j * 16 + l15) * 64 + cc * 8];
#pragma unroll
            for (int i = 0; i < 2; ++i)
#pragma unroll
                for (int j = 0; j < 4; ++j)
                    oacc[i][j] = mfma16(af[i], bf[j], oacc[i][j]);
        }
        __syncthreads();  // single barrier: K/V buffer reuse + DMA drain
    }

    // rowsum reduction across quads (q lives in lanes l, l^16, l^32, l^48)
#pragma unroll
    for (int j = 0; j < 2; ++j) {
        rsum[j] += __shfl_xor(rsum[j], 16, 64);
        rsum[j] += __shfl_xor(rsum[j], 32, 64);
    }
    if (lane < 16) {
        lsi[w * 32 + lane] = 1.0f / rsum[0];
        lsi[w * 32 + 16 + lane] = 1.0f / rsum[1];
    }
    // lsi rows are wave-private: same-wave LDS ordering suffices, no barrier

    long otok = tok0 + (long)qt * 128;
#pragma unroll
    for (int i = 0; i < 2; ++i) {
        int qrow = w * 32 + i * 16 + quad * 4;
#pragma unroll
        for (int j = 0; j < 4; ++j) {
            int d = j * 16 + l15;
#pragma unroll
            for (int r = 0; r < 4; ++r) {
                float v = oacc[i][j][r] * lsi[qrow + r];
                Op[(otok + qrow + r) * 1024 + h * 64 + d] = (f16)v;
            }
        }
    }
}

// Fused fp32->fp16 conversion: q,k,v (8.4M elems each) + 4 weights (1M each).
__global__ void cvt_all(const float* __restrict__ q, const float* __restrict__ k,
                        const float* __restrict__ v, const float* __restrict__ w0,
                        const float* __restrict__ w1, const float* __restrict__ w2,
                        const float* __restrict__ w3, f16* __restrict__ qh,
                        f16* __restrict__ kh, f16* __restrict__ vh,
                        f16* __restrict__ wh) {
    long id = (long)blockIdx.x * 256 + threadIdx.x;  // 3,670,016 total
    const float* s;
    f16* d;
    long off;
    if (id < 3145728) {
        int which = (int)(id >> 20);
        off = (id & 1048575) * 8;
        s = which == 0 ? q : which == 1 ? k : v;
        d = which == 0 ? qh : which == 1 ? kh : vh;
    } else {
        long id2 = id - 3145728;
        int wi = (int)(id2 >> 17);
        off = (id2 & 131071) * 8;
        s = wi == 0 ? w0 : wi == 1 ? w1 : wi == 2 ? w2 : w3;
        d = wh + (long)wi * 1048576;
    }
    f32x4 a = *(const f32x4*)(s + off);
    f32x4 b = *(const f32x4*)(s + off + 4);
    f16x8 hv;
    hv[0] = (f16)a[0]; hv[1] = (f16)a[1]; hv[2] = (f16)a[2]; hv[3] = (f16)a[3];
    hv[4] = (f16)b[0]; hv[5] = (f16)b[1]; hv[6] = (f16)b[2]; hv[7] = (f16)b[3];
    *(f16x8*)(d + off) = hv;
}

extern "C" void kernel_launch(void* const* d_in, const int* in_sizes, int n_in,
                              void* d_out, int out_size, void* d_ws, size_t ws_size,
                              hipStream_t stream) {
    const float* q  = (const float*)d_in[0];
    const float* k  = (const float*)d_in[1];
    const float* v  = (const float*)d_in[2];
    // d_in[3] padding_mask, d_in[4] sequence_mask: no effect in reference
    const float* Wq = (const float*)d_in[5];
    const float* bq = (const float*)d_in[6];
    const float* Wk = (const float*)d_in[7];
    const float* bk = (const float*)d_in[8];
    const float* Wv = (const float*)d_in[9];
    const float* bv = (const float*)d_in[10];
    const float* Wo = (const float*)d_in[11];
    const float* bo = (const float*)d_in[12];

    // 120 MB workspace, race-free across the merged qkv launch:
    //   qh [  0, 16MB)   kh [ 16, 32MB)   vh [ 32, 48MB)   Wh [ 48, 56MB)
    //   Qp [ 56, 72MB)   Kp [ 72, 88MB)   Vt [ 88,104MB)
    //   Op [104,120MB)  (aliases nothing live during attn/o_proj)
    char* ws = (char*)d_ws;
    f16* qh = (f16*)ws;
    f16* kh = (f16*)(ws + (16L << 20));
    f16* vh = (f16*)(ws + (32L << 20));
    f16* Wh = (f16*)(ws + (48L << 20));
    f16* Qp = (f16*)(ws + (56L << 20));
    f16* Kp = (f16*)(ws + (72L << 20));
    f16* Vt = (f16*)(ws + (88L << 20));
    f16* Op = (f16*)(ws + (104L << 20));

    cvt_all<<<14336, 256, 0, stream>>>(q, k, v, Wq, Wk, Wv, Wo, qh, kh, vh, Wh);

    qkv_proj<<<dim3(64, 8, 3), 256, 0, stream>>>(qh, kh, vh, Wh, bq, bk, bv,
                                                 Qp, Kp, Vt);

    attn128<<<1024, 256, 0, stream>>>(Qp, Kp, Vt, Op);

    o_proj<<<dim3(64, 8), 256, 0, stream>>>(Op, Wh + 3145728, bo, (float*)d_out);
}

// Round 5
// 331.036 us; speedup vs baseline: 1.2289x; 1.2289x over previous
//
#include <hip/hip_runtime.h>
#include <stdint.h>

typedef _Float16 f16;
typedef _Float16 f16x8 __attribute__((ext_vector_type(8)));
typedef _Float16 f16x4 __attribute__((ext_vector_type(4)));
typedef _Float16 f16x2 __attribute__((ext_vector_type(2)));
typedef float f32x4 __attribute__((ext_vector_type(4)));

__device__ __forceinline__ f32x4 mfma16(f16x8 a, f16x8 b, f32x4 c) {
    return __builtin_amdgcn_mfma_f32_16x16x32_f16(a, b, c, 0, 0, 0);
}

// Async global->LDS, 16B per lane. LDS dest = wave-uniform base + lane*16.
__device__ __forceinline__ void gload16(const f16* g, f16* l) {
    __builtin_amdgcn_global_load_lds(
        (const __attribute__((address_space(1))) uint32_t*)g,
        (__attribute__((address_space(3))) uint32_t*)l, 16, 0, 0);
}

// ---------------------------------------------------------------------------
// Shared GEMM body: C[m][n] = (sum_k A[m*1024+k]*B[n*1024+k] + bias) * scale.
// K=1024. 128x128 tile, 4 waves 2x2, 16x16x32 f16 MFMA, global_load_lds
// staging with XOR chunk swizzle folded into per-lane source addresses.
// ---------------------------------------------------------------------------
template <bool OUT16>
__device__ __forceinline__ void gemm_body(const f16* __restrict__ A,
                                          const f16* __restrict__ B,
                                          const float* __restrict__ bias,
                                          void* __restrict__ Cout, long ldo,
                                          int biasrow, float scale,
                                          long m0, long n0, f16* As, f16* Bs) {
    int tid = threadIdx.x;
    int lane = tid & 63, w = tid >> 6;
    int wm = w & 1, wn = w >> 1;
    int l15 = lane & 15, quad = lane >> 4;

    int rg = lane >> 3;        // row within 8-row staging group
    int cg = (lane & 7) ^ rg;  // global chunk index (swizzled)
    const f16* ag[4];
    const f16* bg[4];
    f16* al[4];
    f16* bl[4];
#pragma unroll
    for (int t = 0; t < 4; ++t) {
        int rb = (w * 4 + t) * 8;
        ag[t] = A + (m0 + rb + rg) * 1024 + cg * 8;
        bg[t] = B + (n0 + rb + rg) * 1024 + cg * 8;
        al[t] = &As[rb * 64];
        bl[t] = &Bs[rb * 64];
    }

    f32x4 acc[4][4] = {};

    for (int k0 = 0; k0 < 1024; k0 += 64) {
        __syncthreads();
#pragma unroll
        for (int t = 0; t < 4; ++t) {
            gload16(ag[t] + k0, al[t]);
            gload16(bg[t] + k0, bl[t]);
        }
        __syncthreads();
#pragma unroll
        for (int ks = 0; ks < 2; ++ks) {
            int cc = (ks * 4 + quad) ^ (l15 & 7);
            f16x8 af[4], bf[4];
#pragma unroll
            for (int t = 0; t < 4; ++t) {
                af[t] = *(const f16x8*)&As[(wm * 64 + t * 16 + l15) * 64 + cc * 8];
                bf[t] = *(const f16x8*)&Bs[(wn * 64 + t * 16 + l15) * 64 + cc * 8];
            }
#pragma unroll
            for (int i = 0; i < 4; ++i)
#pragma unroll
                for (int j = 0; j < 4; ++j)
                    acc[i][j] = mfma16(af[i], bf[j], acc[i][j]);
        }
    }

    // C/D layout: col = lane&15, row = quad*4 + reg
#pragma unroll
    for (int i = 0; i < 4; ++i) {
        int mrow = wm * 64 + i * 16 + quad * 4;
#pragma unroll
        for (int j = 0; j < 4; ++j) {
            int ncol = wn * 64 + j * 16 + l15;
            long gn = n0 + ncol;
#pragma unroll
            for (int r = 0; r < 4; ++r) {
                long gm = m0 + mrow + r;
                float v = (acc[i][j][r] + (biasrow ? bias[gm] : bias[gn])) * scale;
                if constexpr (OUT16)
                    ((f16*)Cout)[gm * ldo + gn] = (f16)v;
                else
                    ((float*)Cout)[gm * ldo + gn] = v;
            }
        }
    }
}

// Merged Q/K/V projection: grid (64, 8, 3); z selects operand set.
// z=0: Qp = (q@Wq^T+bq)*log2e/32  (softmax scale folded -> attn uses exp2)
// z=1: Kp = k@Wk^T+bk
// z=2: Vt = (v@Wv^T+bv)^T  computed as Wv x v^T -> [e][tok], bias per row
// launch_bounds (256,2): allocator free to ~128 VGPR -- NO spills (the
// (256,4) variant forced 64 VGPR -> 100MB of scratch traffic, round 4).
__global__ __launch_bounds__(256, 2) void qkv_proj(
    const f16* __restrict__ qh, const f16* __restrict__ kh,
    const f16* __restrict__ vh, const f16* __restrict__ Wh,
    const float* __restrict__ bq, const float* __restrict__ bk,
    const float* __restrict__ bv, f16* __restrict__ Qp, f16* __restrict__ Kp,
    f16* __restrict__ Vt) {
    __shared__ __align__(16) f16 As[128 * 64];
    __shared__ __align__(16) f16 Bs[128 * 64];
    int z = blockIdx.z;
    const f16* A;
    const f16* B;
    const float* bias;
    f16* C;
    long ldo;
    int biasrow;
    float scale;
    if (z == 0) {
        A = qh; B = Wh; bias = bq; C = Qp; ldo = 1024; biasrow = 0;
        scale = 0.0450842200277786f;  // log2(e)/32
    } else if (z == 1) {
        A = kh; B = Wh + 1048576; bias = bk; C = Kp; ldo = 1024; biasrow = 0;
        scale = 1.0f;
    } else {
        A = Wh + 2097152; B = vh; bias = bv; C = Vt; ldo = 8192; biasrow = 1;
        scale = 1.0f;
    }
    long m0 = (long)(z == 2 ? blockIdx.y : blockIdx.x) * 128;
    long n0 = (long)(z == 2 ? blockIdx.x : blockIdx.y) * 128;
    gemm_body<true>(A, B, bias, C, ldo, biasrow, scale, m0, n0, As, Bs);
}

// Output projection: out = Op@Wo^T + bo (fp32 out)
__global__ __launch_bounds__(256, 2) void o_proj(const f16* __restrict__ Op,
                                                 const f16* __restrict__ Wo,
                                                 const float* __restrict__ bo,
                                                 float* __restrict__ out) {
    __shared__ __align__(16) f16 As[128 * 64];
    __shared__ __align__(16) f16 Bs[128 * 64];
    gemm_body<false>(Op, Wo, bo, out, 1024, 0, 1.0f, (long)blockIdx.x * 128,
                     (long)blockIdx.y * 128, As, Bs);
}

// ---------------------------------------------------------------------------
// Attention: one block per (n, h, 128-q-tile); 32 k-tiles of 64. Unnormalized
// accumulation (logits bounded), divide by rowsum at end. Qp pre-scaled by
// log2e/32 -> P = exp2(S) via raw v_exp_f32 (__builtin_amdgcn_exp2f; the
// libm exp2f added ~4 VALU/value of denormal fixup -- round-4 regression).
// K/V double-buffered via global_load_lds prefetch. QPs holds Q then P (rows
// wave-private -> no barrier between pack and PV; ONE barrier per k-tile).
// XCD-swizzled grid: all 16 q-tiles of one (n,h) on one XCD.
// ---------------------------------------------------------------------------
__global__ __launch_bounds__(256, 3) void attn128(const f16* __restrict__ Qp,
                                                  const f16* __restrict__ Kp,
                                                  const f16* __restrict__ Vt,
                                                  f16* __restrict__ Op) {
    __shared__ __align__(16) f16 QPs[128 * 64];
    __shared__ __align__(16) f16 Ks[2][64 * 64];
    __shared__ __align__(16) f16 Vs[2][64 * 64];
    __shared__ float lsi[128];

    int tid = threadIdx.x;
    int lane = tid & 63, w = tid >> 6;
    int l15 = lane & 15, quad = lane >> 4;
    int b = blockIdx.x;
    int xcd = b & 7, slot = b >> 3;
    int nh = xcd * 8 + (slot >> 4);  // blocks of one (n,h) share an XCD
    int qt = slot & 15;
    int nb = nh >> 4, h = nh & 15;
    long tok0 = (long)nb * 2048;

    int rg = lane >> 3, cg = (lane & 7) ^ rg;

    // stage Q tile (wave-private rows)
    const f16* qsrc = Qp + (tok0 + qt * 128) * 1024 + h * 64;
#pragma unroll
    for (int t = 0; t < 4; ++t) {
        int rb = w * 32 + t * 8;
        gload16(qsrc + (rb + rg) * 1024 + cg * 8, &QPs[rb * 64]);
    }
    // per-lane K/V source pointers (kt = 0) and running prefetch pointers
    const f16* kptr = Kp + (tok0 + w * 16 + rg) * 1024 + h * 64 + cg * 8;
    const f16* vptr = Vt + ((long)h * 64 + w * 16 + rg) * 8192 + tok0 + cg * 8;
    gload16(kptr, &Ks[0][(w * 16) * 64]);
    gload16(kptr + 8 * 1024, &Ks[0][(w * 16 + 8) * 64]);
    gload16(vptr, &Vs[0][(w * 16) * 64]);
    gload16(vptr + (long)8 * 8192, &Vs[0][(w * 16 + 8) * 64]);
    const f16* kn = kptr + 65536;  // +64 rows * 1024
    const f16* vn = vptr + 64;     // +64 tokens
    __syncthreads();

    // Q fragments are loop-invariant: hoist (QPs becomes P storage after this)
    f16x8 qf[2][2];
#pragma unroll
    for (int ks = 0; ks < 2; ++ks) {
        int cc = (ks * 4 + quad) ^ (l15 & 7);
#pragma unroll
        for (int j = 0; j < 2; ++j)
            qf[ks][j] = *(const f16x8*)&QPs[(w * 32 + j * 16 + l15) * 64 + cc * 8];
    }

    f32x4 oacc[2][4] = {};
    float rsum[2] = {0.f, 0.f};
    const f32x4 z4 = {0.f, 0.f, 0.f, 0.f};

    for (int kt = 0; kt < 32; ++kt) {
        int cur = kt & 1;
        // S^T = K(64 rows) x Q^T; D[k][q], wave w owns q in [w*32, w*32+32)
        f32x4 sacc[4][2];
        {
            int cc0 = quad ^ (l15 & 7);
            int cc1 = (4 + quad) ^ (l15 & 7);
            f16x8 a0[4], a1[4];
#pragma unroll
            for (int t = 0; t < 4; ++t) {
                a0[t] = *(const f16x8*)&Ks[cur][(t * 16 + l15) * 64 + cc0 * 8];
                a1[t] = *(const f16x8*)&Ks[cur][(t * 16 + l15) * 64 + cc1 * 8];
            }
#pragma unroll
            for (int i = 0; i < 4; ++i)
#pragma unroll
                for (int j = 0; j < 2; ++j) {
                    sacc[i][j] = mfma16(a0[i], qf[0][j], z4);
                    sacc[i][j] = mfma16(a1[i], qf[1][j], sacc[i][j]);
                }
        }
        // async prefetch of next K/V tile (overlaps exp/pack below)
        if (kt < 31) {
            int nxt = cur ^ 1;
            f16* kd = &Ks[nxt][(w * 16) * 64];
            f16* vd = &Vs[nxt][(w * 16) * 64];
            gload16(kn, kd);
            gload16(kn + 8 * 1024, kd + 8 * 64);
            gload16(vn, vd);
            gload16(vn + (long)8 * 8192, vd + 8 * 64);
            kn += 65536;
            vn += 64;
        }
        // P = exp2(S); rowsum; pack into QPs (wave-private rows)
#pragma unroll
        for (int i = 0; i < 4; ++i) {
#pragma unroll
            for (int j = 0; j < 2; ++j) {
                float p0 = __builtin_amdgcn_exp2f(sacc[i][j][0]);
                float p1 = __builtin_amdgcn_exp2f(sacc[i][j][1]);
                float p2 = __builtin_amdgcn_exp2f(sacc[i][j][2]);
                float p3 = __builtin_amdgcn_exp2f(sacc[i][j][3]);
                rsum[j] += (p0 + p1) + (p2 + p3);
                f16x2 lo = __builtin_bit_cast(f16x2, __builtin_amdgcn_cvt_pkrtz(p0, p1));
                f16x2 hi = __builtin_bit_cast(f16x2, __builtin_amdgcn_cvt_pkrtz(p2, p3));
                f16x4 ph;
                ph[0] = lo[0]; ph[1] = lo[1]; ph[2] = hi[0]; ph[3] = hi[1];
                int qrow = w * 32 + j * 16 + l15;
                int kl = i * 16 + quad * 4;
                int c = kl >> 3;
                *(f16x4*)&QPs[qrow * 64 + ((c ^ (qrow & 7)) << 3) + (kl & 7)] = ph;
            }
        }
        // O += P(q,k) x V(d,k)^T  (same-wave LDS ordering: no barrier needed)
#pragma unroll
        for (int ks = 0; ks < 2; ++ks) {
            int cc = (ks * 4 + quad) ^ (l15 & 7);
            f16x8 af[2], bf[4];
#pragma unroll
            for (int i = 0; i < 2; ++i)
                af[i] = *(const f16x8*)&QPs[(w * 32 + i * 16 + l15) * 64 + cc * 8];
#pragma unroll
            for (int j = 0; j < 4; ++j)
                bf[j] = *(const f16x8*)&Vs[cur][(j * 16 + l15) * 64 + cc * 8];
#pragma unroll
            for (int i = 0; i < 2; ++i)
#pragma unroll
                for (int j = 0; j < 4; ++j)
                    oacc[i][j] = mfma16(af[i], bf[j], oacc[i][j]);
        }
        __syncthreads();  // single barrier: K/V buffer reuse + DMA drain
    }

    // rowsum reduction across quads (q lives in lanes l, l^16, l^32, l^48)
#pragma unroll
    for (int j = 0; j < 2; ++j) {
        rsum[j] += __shfl_xor(rsum[j], 16, 64);
        rsum[j] += __shfl_xor(rsum[j], 32, 64);
    }
    if (lane < 16) {
        lsi[w * 32 + lane] = 1.0f / rsum[0];
        lsi[w * 32 + 16 + lane] = 1.0f / rsum[1];
    }
    // lsi rows are wave-private: same-wave LDS ordering suffices, no barrier

    long otok = tok0 + (long)qt * 128;
#pragma unroll
    for (int i = 0; i < 2; ++i) {
        int qrow = w * 32 + i * 16 + quad * 4;
#pragma unroll
        for (int j = 0; j < 4; ++j) {
            int d = j * 16 + l15;
#pragma unroll
            for (int r = 0; r < 4; ++r) {
                float v = oacc[i][j][r] * lsi[qrow + r];
                Op[(otok + qrow + r) * 1024 + h * 64 + d] = (f16)v;
            }
        }
    }
}

// Fused fp32->fp16 conversion: q,k,v (8.4M elems each) + 4 weights (1M each).
__global__ void cvt_all(const float* __restrict__ q, const float* __restrict__ k,
                        const float* __restrict__ v, const float* __restrict__ w0,
                        const float* __restrict__ w1, const float* __restrict__ w2,
                        const float* __restrict__ w3, f16* __restrict__ qh,
                        f16* __restrict__ kh, f16* __restrict__ vh,
                        f16* __restrict__ wh) {
    long id = (long)blockIdx.x * 256 + threadIdx.x;  // 3,670,016 total
    const float* s;
    f16* d;
    long off;
    if (id < 3145728) {
        int which = (int)(id >> 20);
        off = (id & 1048575) * 8;
        s = which == 0 ? q : which == 1 ? k : v;
        d = which == 0 ? qh : which == 1 ? kh : vh;
    } else {
        long id2 = id - 3145728;
        int wi = (int)(id2 >> 17);
        off = (id2 & 131071) * 8;
        s = wi == 0 ? w0 : wi == 1 ? w1 : wi == 2 ? w2 : w3;
        d = wh + (long)wi * 1048576;
    }
    f32x4 a = *(const f32x4*)(s + off);
    f32x4 b = *(const f32x4*)(s + off + 4);
    f16x8 hv;
    hv[0] = (f16)a[0]; hv[1] = (f16)a[1]; hv[2] = (f16)a[2]; hv[3] = (f16)a[3];
    hv[4] = (f16)b[0]; hv[5] = (f16)b[1]; hv[6] = (f16)b[2]; hv[7] = (f16)b[3];
    *(f16x8*)(d + off) = hv;
}

extern "C" void kernel_launch(void* const* d_in, const int* in_sizes, int n_in,
                              void* d_out, int out_size, void* d_ws, size_t ws_size,
                              hipStream_t stream) {
    const float* q  = (const float*)d_in[0];
    const float* k  = (const float*)d_in[1];
    const float* v  = (const float*)d_in[2];
    // d_in[3] padding_mask, d_in[4] sequence_mask: no effect in reference
    const float* Wq = (const float*)d_in[5];
    const float* bq = (const float*)d_in[6];
    const float* Wk = (const float*)d_in[7];
    const float* bk = (const float*)d_in[8];
    const float* Wv = (const float*)d_in[9];
    const float* bv = (const float*)d_in[10];
    const float* Wo = (const float*)d_in[11];
    const float* bo = (const float*)d_in[12];

    // 120 MB workspace, race-free across the merged qkv launch:
    //   qh [  0, 16MB)   kh [ 16, 32MB)   vh [ 32, 48MB)   Wh [ 48, 56MB)
    //   Qp [ 56, 72MB)   Kp [ 72, 88MB)   Vt [ 88,104MB)   Op [104,120MB)
    char* ws = (char*)d_ws;
    f16* qh = (f16*)ws;
    f16* kh = (f16*)(ws + (16L << 20));
    f16* vh = (f16*)(ws + (32L << 20));
    f16* Wh = (f16*)(ws + (48L << 20));
    f16* Qp = (f16*)(ws + (56L << 20));
    f16* Kp = (f16*)(ws + (72L << 20));
    f16* Vt = (f16*)(ws + (88L << 20));
    f16* Op = (f16*)(ws + (104L << 20));

    cvt_all<<<14336, 256, 0, stream>>>(q, k, v, Wq, Wk, Wv, Wo, qh, kh, vh, Wh);

    qkv_proj<<<dim3(64, 8, 3), 256, 0, stream>>>(qh, kh, vh, Wh, bq, bk, bv,
                                                 Qp, Kp, Vt);

    attn128<<<1024, 256, 0, stream>>>(Qp, Kp, Vt, Op);

    o_proj<<<dim3(64, 8), 256, 0, stream>>>(Op, Wh + 3145728, bo, (float*)d_out);
}

// Round 6
// 321.428 us; speedup vs baseline: 1.2656x; 1.0299x over previous
//
#include <hip/hip_runtime.h>
#include <stdint.h>

typedef _Float16 f16;
typedef _Float16 f16x8 __attribute__((ext_vector_type(8)));
typedef _Float16 f16x4 __attribute__((ext_vector_type(4)));
typedef _Float16 f16x2 __attribute__((ext_vector_type(2)));
typedef float f32x4 __attribute__((ext_vector_type(4)));

__device__ __forceinline__ f32x4 mfma16(f16x8 a, f16x8 b, f32x4 c) {
    return __builtin_amdgcn_mfma_f32_16x16x32_f16(a, b, c, 0, 0, 0);
}

// Async global->LDS, 16B per lane. LDS dest = wave-uniform base + lane*16.
__device__ __forceinline__ void gload16(const f16* g, f16* l) {
    __builtin_amdgcn_global_load_lds(
        (const __attribute__((address_space(1))) uint32_t*)g,
        (__attribute__((address_space(3))) uint32_t*)l, 16, 0, 0);
}

// ---------------------------------------------------------------------------
// Shared GEMM body: C[m][n] = (sum_k A[m*1024+k]*B[n*1024+k] + bias) * scale.
// K=1024. 128x128 tile, 4 waves 2x2, 16x16x32 f16 MFMA, global_load_lds
// staging with XOR chunk swizzle folded into per-lane source addresses.
// ---------------------------------------------------------------------------
template <bool OUT16>
__device__ __forceinline__ void gemm_body(const f16* __restrict__ A,
                                          const f16* __restrict__ B,
                                          const float* __restrict__ bias,
                                          void* __restrict__ Cout, long ldo,
                                          int biasrow, float scale,
                                          long m0, long n0, f16* As, f16* Bs) {
    int tid = threadIdx.x;
    int lane = tid & 63, w = tid >> 6;
    int wm = w & 1, wn = w >> 1;
    int l15 = lane & 15, quad = lane >> 4;

    int rg = lane >> 3;        // row within 8-row staging group
    int cg = (lane & 7) ^ rg;  // global chunk index (swizzled)
    const f16* ag[4];
    const f16* bg[4];
    f16* al[4];
    f16* bl[4];
#pragma unroll
    for (int t = 0; t < 4; ++t) {
        int rb = (w * 4 + t) * 8;
        ag[t] = A + (m0 + rb + rg) * 1024 + cg * 8;
        bg[t] = B + (n0 + rb + rg) * 1024 + cg * 8;
        al[t] = &As[rb * 64];
        bl[t] = &Bs[rb * 64];
    }

    f32x4 acc[4][4] = {};

    for (int k0 = 0; k0 < 1024; k0 += 64) {
        __syncthreads();
#pragma unroll
        for (int t = 0; t < 4; ++t) {
            gload16(ag[t] + k0, al[t]);
            gload16(bg[t] + k0, bl[t]);
        }
        __syncthreads();
#pragma unroll
        for (int ks = 0; ks < 2; ++ks) {
            int cc = (ks * 4 + quad) ^ (l15 & 7);
            f16x8 af[4], bf[4];
#pragma unroll
            for (int t = 0; t < 4; ++t) {
                af[t] = *(const f16x8*)&As[(wm * 64 + t * 16 + l15) * 64 + cc * 8];
                bf[t] = *(const f16x8*)&Bs[(wn * 64 + t * 16 + l15) * 64 + cc * 8];
            }
#pragma unroll
            for (int i = 0; i < 4; ++i)
#pragma unroll
                for (int j = 0; j < 4; ++j)
                    acc[i][j] = mfma16(af[i], bf[j], acc[i][j]);
        }
    }

    // C/D layout: col = lane&15, row = quad*4 + reg
#pragma unroll
    for (int i = 0; i < 4; ++i) {
        int mrow = wm * 64 + i * 16 + quad * 4;
#pragma unroll
        for (int j = 0; j < 4; ++j) {
            int ncol = wn * 64 + j * 16 + l15;
            long gn = n0 + ncol;
#pragma unroll
            for (int r = 0; r < 4; ++r) {
                long gm = m0 + mrow + r;
                float v = (acc[i][j][r] + (biasrow ? bias[gm] : bias[gn])) * scale;
                if constexpr (OUT16)
                    ((f16*)Cout)[gm * ldo + gn] = (f16)v;
                else
                    ((float*)Cout)[gm * ldo + gn] = v;
            }
        }
    }
}

// Merged Q/K/V projection: grid (64, 8, 3); z selects operand set.
// z=0: Qp = (q@Wq^T+bq)*log2e/32  (softmax scale folded -> attn uses exp2)
// z=1: Kp = k@Wk^T+bk
// z=2: Vt = (v@Wv^T+bv)^T  computed as Wv x v^T -> [e][tok], bias per row
// launch_bounds (256,2): allocator free to ~128+ VGPR -- NO spills (the
// (256,4) variant forced 64 VGPR -> 100MB of scratch traffic, round 4).
__global__ __launch_bounds__(256, 2) void qkv_proj(
    const f16* __restrict__ qh, const f16* __restrict__ kh,
    const f16* __restrict__ vh, const f16* __restrict__ Wh,
    const float* __restrict__ bq, const float* __restrict__ bk,
    const float* __restrict__ bv, f16* __restrict__ Qp, f16* __restrict__ Kp,
    f16* __restrict__ Vt) {
    __shared__ __align__(16) f16 As[128 * 64];
    __shared__ __align__(16) f16 Bs[128 * 64];
    int z = blockIdx.z;
    const f16* A;
    const f16* B;
    const float* bias;
    f16* C;
    long ldo;
    int biasrow;
    float scale;
    if (z == 0) {
        A = qh; B = Wh; bias = bq; C = Qp; ldo = 1024; biasrow = 0;
        scale = 0.0450842200277786f;  // log2(e)/32
    } else if (z == 1) {
        A = kh; B = Wh + 1048576; bias = bk; C = Kp; ldo = 1024; biasrow = 0;
        scale = 1.0f;
    } else {
        A = Wh + 2097152; B = vh; bias = bv; C = Vt; ldo = 8192; biasrow = 1;
        scale = 1.0f;
    }
    long m0 = (long)(z == 2 ? blockIdx.y : blockIdx.x) * 128;
    long n0 = (long)(z == 2 ? blockIdx.x : blockIdx.y) * 128;
    gemm_body<true>(A, B, bias, C, ldo, biasrow, scale, m0, n0, As, Bs);
}

// Output projection: out = Op@Wo^T + bo (fp32 out)
__global__ __launch_bounds__(256, 2) void o_proj(const f16* __restrict__ Op,
                                                 const f16* __restrict__ Wo,
                                                 const float* __restrict__ bo,
                                                 float* __restrict__ out) {
    __shared__ __align__(16) f16 As[128 * 64];
    __shared__ __align__(16) f16 Bs[128 * 64];
    gemm_body<false>(Op, Wo, bo, out, 1024, 0, 1.0f, (long)blockIdx.x * 128,
                     (long)blockIdx.y * 128, As, Bs);
}

// ---------------------------------------------------------------------------
// Attention v3: one block per (n, h, 256-row q-PAIR); 512 blocks = exactly
// 2/CU resident -> zero dispatch tail. Two 128-row q-tiles share each staged
// K/V tile: K fragments feed both S-MFMAs, V fragments feed both PV-MFMAs
// (LDS b128 reads drop 40->24 per equivalent work). Unnormalized softmax
// (logits bounded), Qp pre-scaled by log2e/32 -> raw v_exp_f32. K/V double-
// buffered via global_load_lds prefetch. Ps0 reuses Q0 staging; Ps1 separate;
// P rows wave-private -> single barrier per k-tile. LDS = 64 KB exactly
// (lsi aliases dead Ks after the loop). XCD-swizzled grid.
// ---------------------------------------------------------------------------
__global__ __launch_bounds__(256, 2) void attn256(const f16* __restrict__ Qp,
                                                  const f16* __restrict__ Kp,
                                                  const f16* __restrict__ Vt,
                                                  f16* __restrict__ Op) {
    __shared__ __align__(16) f16 Ps0[128 * 64];
    __shared__ __align__(16) f16 Ps1[128 * 64];
    __shared__ __align__(16) f16 Ks[2][64 * 64];
    __shared__ __align__(16) f16 Vs[2][64 * 64];

    int tid = threadIdx.x;
    int lane = tid & 63, w = tid >> 6;
    int l15 = lane & 15, quad = lane >> 4;
    int b = blockIdx.x;
    int xcd = b & 7, slot = b >> 3;        // 64 slots per XCD
    int nh = xcd * 8 + (slot >> 3);        // 8 (n,h) per XCD
    int qp = slot & 7;                     // 8 q-pairs per (n,h)
    int nb = nh >> 4, h = nh & 15;
    long tok0 = (long)nb * 2048;
    long qrow0 = qp * 256;

    int rg = lane >> 3, cg = (lane & 7) ^ rg;

    // stage both Q tiles (wave-private rows: wave w stages & reads rows w*32..)
    const f16* qsrc0 = Qp + (tok0 + qrow0) * 1024 + h * 64;
    const f16* qsrc1 = qsrc0 + 128 * 1024;
#pragma unroll
    for (int t = 0; t < 4; ++t) {
        int rb = w * 32 + t * 8;
        gload16(qsrc0 + (rb + rg) * 1024 + cg * 8, &Ps0[rb * 64]);
        gload16(qsrc1 + (rb + rg) * 1024 + cg * 8, &Ps1[rb * 64]);
    }
    // K/V tile 0
    const f16* kptr = Kp + (tok0 + w * 16 + rg) * 1024 + h * 64 + cg * 8;
    const f16* vptr = Vt + ((long)h * 64 + w * 16 + rg) * 8192 + tok0 + cg * 8;
    gload16(kptr, &Ks[0][(w * 16) * 64]);
    gload16(kptr + 8 * 1024, &Ks[0][(w * 16 + 8) * 64]);
    gload16(vptr, &Vs[0][(w * 16) * 64]);
    gload16(vptr + (long)8 * 8192, &Vs[0][(w * 16 + 8) * 64]);
    const f16* kn = kptr + 65536;
    const f16* vn = vptr + 64;
    __syncthreads();

    // hoist Q fragments for both tiles (Ps0/Ps1 then become P storage)
    f16x8 qf0[2][2], qf1[2][2];
#pragma unroll
    for (int ks = 0; ks < 2; ++ks) {
        int cc = (ks * 4 + quad) ^ (l15 & 7);
#pragma unroll
        for (int j = 0; j < 2; ++j) {
            qf0[ks][j] = *(const f16x8*)&Ps0[(w * 32 + j * 16 + l15) * 64 + cc * 8];
            qf1[ks][j] = *(const f16x8*)&Ps1[(w * 32 + j * 16 + l15) * 64 + cc * 8];
        }
    }

    f32x4 oacc0[2][4] = {}, oacc1[2][4] = {};
    float rs0[2] = {0.f, 0.f}, rs1[2] = {0.f, 0.f};
    const f32x4 z4 = {0.f, 0.f, 0.f, 0.f};

    for (int kt = 0; kt < 32; ++kt) {
        int cur = kt & 1;
        // S tiles: K fragments read ONCE, feed both q-tiles
        f32x4 sacc0[4][2], sacc1[4][2];
#pragma unroll
        for (int ks = 0; ks < 2; ++ks) {
            int cc = (ks * 4 + quad) ^ (l15 & 7);
            f16x8 a[4];
#pragma unroll
            for (int t = 0; t < 4; ++t)
                a[t] = *(const f16x8*)&Ks[cur][(t * 16 + l15) * 64 + cc * 8];
#pragma unroll
            for (int i = 0; i < 4; ++i)
#pragma unroll
                for (int j = 0; j < 2; ++j) {
                    if (ks == 0) {
                        sacc0[i][j] = mfma16(a[i], qf0[0][j], z4);
                        sacc1[i][j] = mfma16(a[i], qf1[0][j], z4);
                    } else {
                        sacc0[i][j] = mfma16(a[i], qf0[1][j], sacc0[i][j]);
                        sacc1[i][j] = mfma16(a[i], qf1[1][j], sacc1[i][j]);
                    }
                }
        }
        // async prefetch next K/V tile (overlaps exp/pack)
        if (kt < 31) {
            int nxt = cur ^ 1;
            f16* kd = &Ks[nxt][(w * 16) * 64];
            f16* vd = &Vs[nxt][(w * 16) * 64];
            gload16(kn, kd);
            gload16(kn + 8 * 1024, kd + 8 * 64);
            gload16(vn, vd);
            gload16(vn + (long)8 * 8192, vd + 8 * 64);
            kn += 65536;
            vn += 64;
        }
        // exp + rowsum + pack for both tiles (wave-private rows)
#pragma unroll
        for (int i = 0; i < 4; ++i) {
#pragma unroll
            for (int j = 0; j < 2; ++j) {
                int qrow = w * 32 + j * 16 + l15;
                int kl = i * 16 + quad * 4;
                int c = kl >> 3;
                int off = qrow * 64 + ((c ^ (qrow & 7)) << 3) + (kl & 7);
                {
                    float p0 = __builtin_amdgcn_exp2f(sacc0[i][j][0]);
                    float p1 = __builtin_amdgcn_exp2f(sacc0[i][j][1]);
                    float p2 = __builtin_amdgcn_exp2f(sacc0[i][j][2]);
                    float p3 = __builtin_amdgcn_exp2f(sacc0[i][j][3]);
                    rs0[j] += (p0 + p1) + (p2 + p3);
                    f16x2 lo = __builtin_bit_cast(f16x2, __builtin_amdgcn_cvt_pkrtz(p0, p1));
                    f16x2 hi = __builtin_bit_cast(f16x2, __builtin_amdgcn_cvt_pkrtz(p2, p3));
                    f16x4 ph;
                    ph[0] = lo[0]; ph[1] = lo[1]; ph[2] = hi[0]; ph[3] = hi[1];
                    *(f16x4*)&Ps0[off] = ph;
                }
                {
                    float p0 = __builtin_amdgcn_exp2f(sacc1[i][j][0]);
                    float p1 = __builtin_amdgcn_exp2f(sacc1[i][j][1]);
                    float p2 = __builtin_amdgcn_exp2f(sacc1[i][j][2]);
                    float p3 = __builtin_amdgcn_exp2f(sacc1[i][j][3]);
                    rs1[j] += (p0 + p1) + (p2 + p3);
                    f16x2 lo = __builtin_bit_cast(f16x2, __builtin_amdgcn_cvt_pkrtz(p0, p1));
                    f16x2 hi = __builtin_bit_cast(f16x2, __builtin_amdgcn_cvt_pkrtz(p2, p3));
                    f16x4 ph;
                    ph[0] = lo[0]; ph[1] = lo[1]; ph[2] = hi[0]; ph[3] = hi[1];
                    *(f16x4*)&Ps1[off] = ph;
                }
            }
        }
        // PV: V fragments read ONCE, feed both q-tiles
#pragma unroll
        for (int ks = 0; ks < 2; ++ks) {
            int cc = (ks * 4 + quad) ^ (l15 & 7);
            f16x8 bf[4];
#pragma unroll
            for (int j = 0; j < 4; ++j)
                bf[j] = *(const f16x8*)&Vs[cur][(j * 16 + l15) * 64 + cc * 8];
            f16x8 af0[2], af1[2];
#pragma unroll
            for (int i = 0; i < 2; ++i) {
                af0[i] = *(const f16x8*)&Ps0[(w * 32 + i * 16 + l15) * 64 + cc * 8];
                af1[i] = *(const f16x8*)&Ps1[(w * 32 + i * 16 + l15) * 64 + cc * 8];
            }
#pragma unroll
            for (int i = 0; i < 2; ++i)
#pragma unroll
                for (int j = 0; j < 4; ++j) {
                    oacc0[i][j] = mfma16(af0[i], bf[j], oacc0[i][j]);
                    oacc1[i][j] = mfma16(af1[i], bf[j], oacc1[i][j]);
                }
        }
        __syncthreads();  // single barrier: K/V buffer reuse + DMA drain
    }

    // rowsum reduction across quads; lsi aliases dead Ks (post-loop barrier
    // already passed; writes/reads are wave-private rows)
    float* lsi = (float*)&Ks[0][0];  // 256 floats
#pragma unroll
    for (int j = 0; j < 2; ++j) {
        rs0[j] += __shfl_xor(rs0[j], 16, 64);
        rs0[j] += __shfl_xor(rs0[j], 32, 64);
        rs1[j] += __shfl_xor(rs1[j], 16, 64);
        rs1[j] += __shfl_xor(rs1[j], 32, 64);
    }
    if (lane < 16) {
        lsi[w * 32 + lane] = 1.0f / rs0[0];
        lsi[w * 32 + 16 + lane] = 1.0f / rs0[1];
        lsi[128 + w * 32 + lane] = 1.0f / rs1[0];
        lsi[128 + w * 32 + 16 + lane] = 1.0f / rs1[1];
    }

    long otok = tok0 + qrow0;
#pragma unroll
    for (int i = 0; i < 2; ++i) {
        int qrow = w * 32 + i * 16 + quad * 4;
#pragma unroll
        for (int j = 0; j < 4; ++j) {
            int d = j * 16 + l15;
#pragma unroll
            for (int r = 0; r < 4; ++r) {
                Op[(otok + qrow + r) * 1024 + h * 64 + d] =
                    (f16)(oacc0[i][j][r] * lsi[qrow + r]);
                Op[(otok + 128 + qrow + r) * 1024 + h * 64 + d] =
                    (f16)(oacc1[i][j][r] * lsi[128 + qrow + r]);
            }
        }
    }
}

// Fused fp32->fp16 conversion: q,k,v (8.4M elems each) + 4 weights (1M each).
__global__ void cvt_all(const float* __restrict__ q, const float* __restrict__ k,
                        const float* __restrict__ v, const float* __restrict__ w0,
                        const float* __restrict__ w1, const float* __restrict__ w2,
                        const float* __restrict__ w3, f16* __restrict__ qh,
                        f16* __restrict__ kh, f16* __restrict__ vh,
                        f16* __restrict__ wh) {
    long id = (long)blockIdx.x * 256 + threadIdx.x;  // 3,670,016 total
    const float* s;
    f16* d;
    long off;
    if (id < 3145728) {
        int which = (int)(id >> 20);
        off = (id & 1048575) * 8;
        s = which == 0 ? q : which == 1 ? k : v;
        d = which == 0 ? qh : which == 1 ? kh : vh;
    } else {
        long id2 = id - 3145728;
        int wi = (int)(id2 >> 17);
        off = (id2 & 131071) * 8;
        s = wi == 0 ? w0 : wi == 1 ? w1 : wi == 2 ? w2 : w3;
        d = wh + (long)wi * 1048576;
    }
    f32x4 a = *(const f32x4*)(s + off);
    f32x4 b = *(const f32x4*)(s + off + 4);
    f16x8 hv;
    hv[0] = (f16)a[0]; hv[1] = (f16)a[1]; hv[2] = (f16)a[2]; hv[3] = (f16)a[3];
    hv[4] = (f16)b[0]; hv[5] = (f16)b[1]; hv[6] = (f16)b[2]; hv[7] = (f16)b[3];
    *(f16x8*)(d + off) = hv;
}

extern "C" void kernel_launch(void* const* d_in, const int* in_sizes, int n_in,
                              void* d_out, int out_size, void* d_ws, size_t ws_size,
                              hipStream_t stream) {
    const float* q  = (const float*)d_in[0];
    const float* k  = (const float*)d_in[1];
    const float* v  = (const float*)d_in[2];
    // d_in[3] padding_mask, d_in[4] sequence_mask: no effect in reference
    const float* Wq = (const float*)d_in[5];
    const float* bq = (const float*)d_in[6];
    const float* Wk = (const float*)d_in[7];
    const float* bk = (const float*)d_in[8];
    const float* Wv = (const float*)d_in[9];
    const float* bv = (const float*)d_in[10];
    const float* Wo = (const float*)d_in[11];
    const float* bo = (const float*)d_in[12];

    // 120 MB workspace, race-free across the merged qkv launch:
    //   qh [  0, 16MB)   kh [ 16, 32MB)   vh [ 32, 48MB)   Wh [ 48, 56MB)
    //   Qp [ 56, 72MB)   Kp [ 72, 88MB)   Vt [ 88,104MB)   Op [104,120MB)
    char* ws = (char*)d_ws;
    f16* qh = (f16*)ws;
    f16* kh = (f16*)(ws + (16L << 20));
    f16* vh = (f16*)(ws + (32L << 20));
    f16* Wh = (f16*)(ws + (48L << 20));
    f16* Qp = (f16*)(ws + (56L << 20));
    f16* Kp = (f16*)(ws + (72L << 20));
    f16* Vt = (f16*)(ws + (88L << 20));
    f16* Op = (f16*)(ws + (104L << 20));

    cvt_all<<<14336, 256, 0, stream>>>(q, k, v, Wq, Wk, Wv, Wo, qh, kh, vh, Wh);

    qkv_proj<<<dim3(64, 8, 3), 256, 0, stream>>>(qh, kh, vh, Wh, bq, bk, bv,
                                                 Qp, Kp, Vt);

    attn256<<<512, 256, 0, stream>>>(Qp, Kp, Vt, Op);

    o_proj<<<dim3(64, 8), 256, 0, stream>>>(Op, Wh + 3145728, bo, (float*)d_out);
}